// Round 10
// baseline (76.126 us; speedup 1.0000x reference)
//
#include <hip/hip_runtime.h>
#include <math.h>

// RangeAwareL1Loss on MI355X — two-pass; pass 1 counts via CUMULATIVE THRESHOLDS.
// Wall inventory (R1-R8): per-elem LDS atomic ~42us, 31-ballot ~42us, 16-way select ~48us.
// New counting: C[k] = #{t >= log1p(k)}, k=0..30 -> per element 31x (v_cmp lit + v_addc),
// pure VALU ~13us. counts[b] = C[b]-C[b+1]; total_valid = C[0] (valid <=> t>=0, verified
// absmax=0 in R5-R7). Pass 2 (wsum) is R5's proven kernel (~free: inputs L3-resident).
// ws: g_part[nblk][32] u32; +128B-aligned g_w (31 w + tv); then partials[nblk] f32.

#define NBLK 2048
#define NTHR 256

// fast bin for the w-lookup: for t >= 0, floor(expm1(t)) == (int)exp2(t*log2e) - 1
__device__ __forceinline__ int fast_bin(float t) {
    float ex = __builtin_amdgcn_exp2f(t * 1.4426950408889634f);
    int b = (int)ex - 1;
    return (b > 30) ? 30 : b;
}

__global__ __launch_bounds__(256) void hist_kernel(const float* __restrict__ target,
                                                   unsigned int* __restrict__ g_part,
                                                   int n4, int nblk) {
    constexpr float TH[31] = {
        0.0f,        0.69314718f, 1.09861229f, 1.38629436f, 1.60943791f,
        1.79175947f, 1.94591015f, 2.07944154f, 2.19722458f, 2.30258509f,
        2.39789527f, 2.48490665f, 2.56494936f, 2.63905733f, 2.70805020f,
        2.77258872f, 2.83321334f, 2.89037176f, 2.94443898f, 2.99573227f,
        3.04452244f, 3.09104245f, 3.13549422f, 3.17805383f, 3.21887582f,
        3.25809654f, 3.29583687f, 3.33220451f, 3.36729583f, 3.40119738f,
        3.43398720f};
    __shared__ unsigned int pa[4][31];
    __shared__ unsigned int bc[31];
    const int tid = threadIdx.x, lane = tid & 63, wid = tid >> 6;

    unsigned int acc[31];
#pragma unroll
    for (int k = 0; k < 31; ++k) acc[k] = 0u;

    const float4* t4 = (const float4*)target;
    for (int i = blockIdx.x * NTHR + tid; i < n4; i += nblk * NTHR) {
        float4 tv = t4[i];
#pragma unroll
        for (int e = 0; e < 4; ++e) {
            float t = (&tv.x)[e];
#pragma unroll
            for (int k = 0; k < 31; ++k)
                acc[k] += (unsigned int)(t >= TH[k]);   // v_cmp(lit) + v_addc: 2 VALU, 0 SALU
        }
    }

    // wave-reduce each of the 31 counters (static unroll; once per kernel)
#pragma unroll
    for (int k = 0; k < 31; ++k) {
        unsigned int v = acc[k];
#pragma unroll
        for (int off = 32; off > 0; off >>= 1) v += __shfl_down(v, off, 64);
        acc[k] = v;
    }
    if (lane == 0) {
#pragma unroll
        for (int k = 0; k < 31; ++k) pa[wid][k] = acc[k];
    }
    __syncthreads();
    if (tid < 31) bc[tid] = pa[0][tid] + pa[1][tid] + pa[2][tid] + pa[3][tid];
    __syncthreads();
    // per-bin counts = adjacent differences; col 31 = total_valid = C[0]
    if (tid < 31) {
        unsigned int c = bc[tid] - ((tid < 30) ? bc[tid + 1] : 0u);
        g_part[blockIdx.x * 32 + tid] = c;
    } else if (tid == 31) {
        g_part[blockIdx.x * 32 + 31] = bc[0];
    }
}

// reduce nblk x 32 u32 -> weights w[0..30] and float total_valid in g_w[31]
__global__ __launch_bounds__(1024) void wred_kernel(const unsigned int* __restrict__ g_part,
                                                    float* __restrict__ g_w, int nblk) {
    __shared__ unsigned int ssum[32][33];
    __shared__ unsigned int tot[32];
    const int tid = threadIdx.x, col = tid & 31, grp = tid >> 5;
    unsigned int s = 0;
    for (int r = grp; r < nblk; r += 32) s += g_part[r * 32 + col];   // coalesced
    ssum[grp][col] = s;
    __syncthreads();
    if (tid < 32) {
        unsigned int c = 0;
#pragma unroll
        for (int g = 0; g < 32; ++g) c += ssum[g][tid];
        tot[tid] = c;
    }
    __syncthreads();
    if (tid < 31) {
        float tv   = (float)tot[31];                 // valid < 2^24: exact in f32
        float freq = (float)tot[tid] / tv;
        g_w[tid]   = 1.0f / (sqrtf(freq) + 1e-6f);   // ALPHA=0.5, EPS=1e-6
    }
    if (tid == 31) g_w[31] = (float)tot[31];
}

__global__ __launch_bounds__(256) void wsum_kernel(const float* __restrict__ pred,
                                                   const float* __restrict__ target,
                                                   const float* __restrict__ g_w,
                                                   float* __restrict__ partials,
                                                   int n4, int nblk) {
    __shared__ float w_s[31];
    __shared__ float red[4];
    const int tid = threadIdx.x;
    if (tid < 31) w_s[tid] = g_w[tid];
    __syncthreads();

    float s = 0.0f;
    const float4* t4 = (const float4*)target;
    const float4* p4 = (const float4*)pred;
    for (int i = blockIdx.x * NTHR + tid; i < n4; i += nblk * NTHR) {
        float4 tv4 = t4[i];
        float4 pv4 = p4[i];
#pragma unroll
        for (int e = 0; e < 4; ++e) {
            float t = (&tv4.x)[e];
            float p = (&pv4.x)[e];
            if (t >= 0.0f) {
                s += fabsf(p - t) * w_s[fast_bin(t)];   // LDS read: broadcast-cheap
            }
        }
    }
#pragma unroll
    for (int off = 32; off > 0; off >>= 1) s += __shfl_down(s, off, 64);
    if ((tid & 63) == 0) red[tid >> 6] = s;
    __syncthreads();
    if (tid == 0) partials[blockIdx.x] = red[0] + red[1] + red[2] + red[3];
}

__global__ __launch_bounds__(256) void final_kernel(const float* __restrict__ partials,
                                                    const float* __restrict__ g_w,
                                                    float* __restrict__ out, int nblk) {
    __shared__ float red[4];
    const int tid = threadIdx.x;
    float s = 0.0f;
    for (int i = tid; i < nblk; i += 256) s += partials[i];
#pragma unroll
    for (int off = 32; off > 0; off >>= 1) s += __shfl_down(s, off, 64);
    if ((tid & 63) == 0) red[tid >> 6] = s;
    __syncthreads();
    if (tid == 0) out[0] = (red[0] + red[1] + red[2] + red[3]) / g_w[31];
}

extern "C" void kernel_launch(void* const* d_in, const int* in_sizes, int n_in,
                              void* d_out, int out_size, void* d_ws, size_t ws_size,
                              hipStream_t stream) {
    const float* pred   = (const float*)d_in[0];
    const float* target = (const float*)d_in[1];
    float*       out    = (float*)d_out;

    const int n  = in_sizes[0];   // 16,777,216
    const int n4 = n / 4;

    int nblk = NBLK;
    size_t need = (size_t)nblk * 32 * 4 + 128 + (size_t)nblk * 4;
    if (ws_size < need) nblk = 512;

    unsigned int* g_part   = (unsigned int*)d_ws;                              // nblk*32 u32
    float*        g_w      = (float*)((char*)d_ws + (size_t)nblk * 32 * 4);          // 32 f32
    float*        partials = (float*)((char*)d_ws + (size_t)nblk * 32 * 4 + 128);    // nblk f32

    hist_kernel<<<nblk, NTHR, 0, stream>>>(target, g_part, n4, nblk);
    wred_kernel<<<1, 1024, 0, stream>>>(g_part, g_w, nblk);
    wsum_kernel<<<nblk, NTHR, 0, stream>>>(pred, target, g_w, partials, n4, nblk);
    final_kernel<<<1, NTHR, 0, stream>>>(partials, g_w, out, nblk);
}